// Round 9
// baseline (240.180 us; speedup 1.0000x reference)
//
#include <hip/hip_runtime.h>

// SSIM loss, fused. Round 15: single-slot ring -> 16 KB/block -> FULL occupancy.
//  - r14 POST-MORTEM: counted vmcnt was worth only ~1.5us. The real wall is
//    residency: Occupancy 38% (~12 waves/CU, ~3/SIMD) vs LDS cap 20 (32KB
//    ring/block). 3 waves x 550cy VALU per ~6000cy wall = 26% VALUBusy.
//    The grid offers 8 waves/SIMD; LDS is the cap.
//  - FIX: ring shrinks to ONE slot/wave (4KB): stage row orow+7 EARLY
//    (right after consuming orow+6; consume's lgkmcnt(0) makes the slot
//    reuse race-free), giving the DMA the HWIN+ssim+retire phase (~800cy)
//    of shadow; the retire's vmcnt(0) drains it with small residual (r13
//    vs r14 bounded this cost at ~1-2us). One real wait per iteration.
//    16KB/block -> 8 blocks/CU (VGPR=64 allows 8 waves/SIMD) = 32 waves/CU
//    = 100% of cap; grid 2040 blocks = 7.97/CU fills it in one round.
//  - Everything else as r14: BAND=6, WPB=4, 8 cols/lane, 4 register sum
//    planes, shfl halo, retire row = sunk global load (~L2/L3).

#define IW    512
#define OUTW  506
#define BAND  6                  // output rows per wave
#define NBANDS 85                // ceil(506/6); last band does 2 rows
#define NIMG  96
#define WPB   4                  // waves per block
#define NBLK  (NBANDS * NIMG / WPB)   // 2040 blocks
#define NPART NBLK
#define C1N2  0.2401f            // 1e-4 * 49^2
#define C2N2  2.1609f            // 9e-4 * 49^2
#define KA    (49.0f/24.0f)
#define KB    (49.0f/48.0f)
#define TOTAL_OUT 24579456.0f    // 96*506*506

typedef const __attribute__((address_space(1))) unsigned int* gas1_t;
typedef __attribute__((address_space(3))) unsigned int* las3_t;
typedef float v4f __attribute__((ext_vector_type(4)));

// Stage one 2 KB row (512 floats) into LDS: 2 DMA instrs, 1 KB each.
// HW: per-lane GLOBAL src address; LDS dest = uniform base + 16*lane.
__device__ __forceinline__ void stage_row(const float* g, float* l, int lane) {
    __builtin_amdgcn_global_load_lds((gas1_t)(g + 4 * lane),       (las3_t)l,         16, 0, 0);
    __builtin_amdgcn_global_load_lds((gas1_t)(g + 256 + 4 * lane), (las3_t)(l + 256), 16, 0, 0);
}

__device__ __forceinline__ float ssim_raw(float Sx, float Sy, float S2, float Sxy) {
    float sxsy = Sx * Sy;
    float p    = fmaf(Sx, Sx, Sy * Sy);
    float a1   = fmaf(2.0f, sxsy, C1N2);
    float b1   = p + C1N2;
    float a2   = fmaf(KA, fmaf(49.0f, Sxy, -sxsy), C2N2);
    float b2   = fmaf(KB, fmaf(49.0f, S2, -p), C2N2);
    return (a1 * a2) * __builtin_amdgcn_rcpf(b1 * b2);
}

__device__ __forceinline__ void unpack8(float4 a, float4 b, float* d) {
    d[0]=a.x; d[1]=a.y; d[2]=a.z; d[3]=a.w;
    d[4]=b.x; d[5]=b.y; d[6]=b.z; d[7]=b.w;
}

__device__ __forceinline__ void unpack8v(v4f a, v4f b, float* d) {
    d[0]=a.x; d[1]=a.y; d[2]=a.z; d[3]=a.w;
    d[4]=b.x; d[5]=b.y; d[6]=b.z; d[7]=b.w;
}

__global__ __launch_bounds__(256)
void ssim_main(const float* __restrict__ X,
               const float* __restrict__ Y,
               float* __restrict__ partials) {
    // ring[wave][0..511]=X row, [512..1023]=Y row. 16384 B exactly.
    __shared__ float ring[WPB][1024];

    const int t    = threadIdx.x;
    const int wv   = t >> 6;
    const int lane = t & 63;
    const int gw   = blockIdx.x * WPB + wv;      // 0..8159
    const int img  = gw / NBANDS;
    const int band = gw - img * NBANDS;
    const int r0   = band * BAND;
    const float* Xf = X + (size_t)img * IW * IW;
    const float* Yf = Y + (size_t)img * IW * IW;
    const float4* X4 = (const float4*)Xf;
    const float4* Y4 = (const float4*)Yf;
    const int c0 = 2 * lane;                     // float4 index of col 8*lane

    // Kick off DMA for row r0+6: completes under the 6-row prologue
    // (prologue load waits retire the older DMAs first — vmcnt is FIFO).
    stage_row(Xf + (size_t)(r0 + 6) * IW, &ring[wv][0],   lane);
    stage_row(Yf + (size_t)(r0 + 6) * IW, &ring[wv][512], lane);

    // vertical sliding column sums, 8 cols/lane, 4 planes = 32 VGPR
    float sx[8], sy[8], s2[8], sxy[8];
#pragma unroll
    for (int q = 0; q < 8; ++q) { sx[q]=0.f; sy[q]=0.f; s2[q]=0.f; sxy[q]=0.f; }

    // prologue: rows r0 .. r0+5 via direct global loads (24 indep loads)
#pragma unroll
    for (int i = 0; i < 6; ++i) {
        const int ro = (r0 + i) * (IW / 4);
        float4 xa = X4[ro + c0], xb = X4[ro + c0 + 1];
        float4 ya = Y4[ro + c0], yb = Y4[ro + c0 + 1];
        float x[8], y[8];
        unpack8(xa, xb, x); unpack8(ya, yb, y);
#pragma unroll
        for (int q = 0; q < 8; ++q) {
            sx[q] += x[q]; sy[q] += y[q];
            s2[q]  = fmaf(x[q], x[q], s2[q]);
            s2[q]  = fmaf(y[q], y[q], s2[q]);
            sxy[q] = fmaf(x[q], y[q], sxy[q]);
        }
    }

    float accS = 0.0f;

#pragma unroll 1
    for (int r = 0; r < BAND; ++r) {
        const int orow = r0 + r;
        if (orow >= OUTW) break;                 // wave-uniform (last band)

        // ---- consume staged new row (orow+6) from LDS ----
        // vmcnt(0) is ~free: the previous iteration's retire wait already
        // drained everything (steady state). Bundled asm prevents the
        // compiler inserting its own waits or reordering the ds_reads.
        {
            const unsigned a0 =
                (unsigned)(size_t)(las3_t)&ring[wv][0] + 32u * (unsigned)lane;
            v4f xa, xb, ya, yb;
            asm volatile(
                "s_waitcnt vmcnt(0)\n\t"
                "ds_read_b128 %0, %4\n\t"
                "ds_read_b128 %1, %4 offset:16\n\t"
                "ds_read_b128 %2, %4 offset:2048\n\t"
                "ds_read_b128 %3, %4 offset:2064\n\t"
                "s_waitcnt lgkmcnt(0)"
                : "=&v"(xa), "=&v"(xb), "=&v"(ya), "=&v"(yb)
                : "v"(a0)
                : "memory");
            float x[8], y[8];
            unpack8v(xa, xb, x); unpack8v(ya, yb, y);
#pragma unroll
            for (int q = 0; q < 8; ++q) {
                sx[q] += x[q]; sy[q] += y[q];
                s2[q]  = fmaf(x[q], x[q], s2[q]);
                s2[q]  = fmaf(y[q], y[q], s2[q]);
                sxy[q] = fmaf(x[q], y[q], sxy[q]);
            }
        }

        // ---- stage row orow+7 into the SAME slot (race-free: consume's
        // lgkmcnt(0) completed all reads). Shadow = HWIN+ssim+retire
        // (~800cy); the retire vmcnt(0) drains it with small residual.
        __builtin_amdgcn_sched_barrier(0);
        if (r + 1 < BAND && orow + 1 < OUTW) {
            stage_row(Xf + (size_t)(orow + 7) * IW, &ring[wv][0],   lane);
            stage_row(Yf + (size_t)(orow + 7) * IW, &ring[wv][512], lane);
        }
        __builtin_amdgcn_sched_barrier(0);

        // ---- horizontal 7-windows: halo = next lane's first 6 col sums ----
        float Wx[8], Wy[8], W2[8], Wxy[8];
#define HWIN(S, W)                                                         \
        {                                                                  \
            float h0 = __shfl_down(S[0], 1, 64);                           \
            float h1 = __shfl_down(S[1], 1, 64);                           \
            float h2 = __shfl_down(S[2], 1, 64);                           \
            float h3 = __shfl_down(S[3], 1, 64);                           \
            float h4 = __shfl_down(S[4], 1, 64);                           \
            float h5 = __shfl_down(S[5], 1, 64);                           \
            W[0] = ((S[0]+S[1]) + (S[2]+S[3])) + ((S[4]+S[5]) + S[6]);     \
            W[1] = W[0] + (S[7] - S[0]);                                   \
            W[2] = W[1] + (h0   - S[1]);                                   \
            W[3] = W[2] + (h1   - S[2]);                                   \
            W[4] = W[3] + (h2   - S[3]);                                   \
            W[5] = W[4] + (h3   - S[4]);                                   \
            W[6] = W[5] + (h4   - S[5]);                                   \
            W[7] = W[6] + (h5   - S[6]);                                   \
        }
        HWIN(sx,  Wx)
        HWIN(sy,  Wy)
        HWIN(s2,  W2)
        HWIN(sxy, Wxy)
#undef HWIN

        // ---- SSIM at 8 output cols ----
#pragma unroll
        for (int m = 0; m < 8; ++m) {
            float Sv = ssim_raw(Wx[m], Wy[m], W2[m], Wxy[m]);
            accS += (8 * lane + m < OUTW) ? Sv : 0.0f;
        }

        // ---- retire oldest row (orow): sunk global re-read (~L2/L3).
        // Compiler's vmcnt(0) here is the ONE real wait per iteration:
        // covers retire latency and the ~800cy-shadowed DMA residual.
        {
            const int rr = orow * (IW / 4);
            float4 xa = X4[rr + c0], xb = X4[rr + c0 + 1];
            float4 ya = Y4[rr + c0], yb = Y4[rr + c0 + 1];
            float x[8], y[8];
            unpack8(xa, xb, x); unpack8(ya, yb, y);
#pragma unroll
            for (int q = 0; q < 8; ++q) {
                sx[q] -= x[q]; sy[q] -= y[q];
                s2[q]  = fmaf(-x[q], x[q], s2[q]);
                s2[q]  = fmaf(-y[q], y[q], s2[q]);
                sxy[q] = fmaf(-x[q], y[q], sxy[q]);
            }
        }
    }

    // block reduce -> one partial per block. wsum aliases the ring (every
    // staged DMA was consumed -> drained; barrier quiesces the ring).
#pragma unroll
    for (int o = 32; o > 0; o >>= 1)
        accS += __shfl_down(accS, o, 64);
    __syncthreads();                      // ring no longer in use by any wave
    float* wsum = &ring[0][0];
    if (lane == 0) wsum[wv] = accS;
    __syncthreads();
    if (t == 0)
        partials[blockIdx.x] = (wsum[0] + wsum[1]) + (wsum[2] + wsum[3]);
}

__global__ __launch_bounds__(256) void ssim_finalize(const float* __restrict__ partials,
                                                     float* __restrict__ out) {
    __shared__ float wsum[4];
    const int t = threadIdx.x;
    float v = 0.0f;
    for (int i = t; i < NPART; i += 256) v += partials[i];
#pragma unroll
    for (int o = 32; o > 0; o >>= 1)
        v += __shfl_down(v, o, 64);
    if ((t & 63) == 0) wsum[t >> 6] = v;
    __syncthreads();
    if (t == 0)
        out[0] = 1.0f - ((wsum[0] + wsum[1]) + (wsum[2] + wsum[3])) / TOTAL_OUT;
}

extern "C" void kernel_launch(void* const* d_in, const int* in_sizes, int n_in,
                              void* d_out, int out_size, void* d_ws, size_t ws_size,
                              hipStream_t stream) {
    const float* X = (const float*)d_in[0];
    const float* Y = (const float*)d_in[1];
    float* partials = (float*)d_ws;          // NPART floats (8.2 KB)
    float* out = (float*)d_out;

    hipLaunchKernelGGL(ssim_main, dim3(NBLK), dim3(256), 0, stream,
                       X, Y, partials);
    hipLaunchKernelGGL(ssim_finalize, dim3(1), dim3(256), 0, stream,
                       partials, out);
}